// Round 8
// baseline (774.272 us; speedup 1.0000x reference)
//
#include <hip/hip_runtime.h>
#include <math.h>

// Round 8: r7's barrier-free flash + explicit wave-local LDS fences.
// The P C->A transform through LDS is CROSS-LANE: compiler waitcnt insertion
// tracks only per-lane register deps, so without a fence the ds_read_b128s can
// race the ds_write_b64 burst (r7 failed post-timing with absmax 5.02).
// Fix: s_waitcnt lgkmcnt(0) (+ memory clobber) before and after the P-stores.
// Waves still free-run: no __syncthreads anywhere in flash; K/V fragments are
// loaded global->register directly (layouts are 16B/lane contiguous).
// GEMMs: r5 config (128x128 dbuf single-barrier) for all four.
//
// ws: [0,16M) lnbuf | [16,48M) qk | [48,64M) vT | [64,80M) ybuf
//     [80,144M) h | [144,170M) wT

#define M_ROWS 8192
#define T_SEQ 2048
#define N_EMB 1024
#define N_HEADS 16
#define HEAD_D 64

typedef _Float16 f16;
typedef __attribute__((ext_vector_type(8))) _Float16 f16x8;
typedef __attribute__((ext_vector_type(4))) _Float16 f16x4;
typedef __attribute__((ext_vector_type(4))) float f32x4;

// wave-local LDS fence: drain all outstanding DS ops; memory clobber pins
// compiler ordering of LDS accesses across the fence.
#define LDS_FENCE() asm volatile("s_waitcnt lgkmcnt(0)" ::: "memory")

__device__ __forceinline__ void async16(void* lds, const void* g) {
    __builtin_amdgcn_global_load_lds(
        (const __attribute__((address_space(1))) unsigned int*)g,
        (__attribute__((address_space(3))) unsigned int*)lds, 16, 0, 0);
}

__device__ __forceinline__ float gelu_tanh(float v) {
    float u = 0.7978845608028654f * (v + 0.044715f * v * v * v);
    float e = __expf(2.0f * u);
    float t = 1.0f - 2.0f / (e + 1.0f);
    return 0.5f * v * (1.0f + t);
}

// ---------------------------------------------------------------- weight convert
__launch_bounds__(256)
__global__ void wconv_kernel(const float* __restrict__ W, f16* __restrict__ WT,
                             int K, int N) {
    __shared__ float t[32][33];
    int tx = threadIdx.x & 31, ty = threadIdx.x >> 5;
    int n0 = blockIdx.x * 32, k0 = blockIdx.y * 32;
    #pragma unroll
    for (int r = 0; r < 4; r++)
        t[ty * 4 + r][tx] = W[(size_t)(k0 + ty * 4 + r) * N + n0 + tx];
    __syncthreads();
    #pragma unroll
    for (int r = 0; r < 4; r++)
        WT[(size_t)(n0 + ty * 4 + r) * K + k0 + tx] = (f16)t[tx][ty * 4 + r];
}

// ---------------------------------------------------------------- LayerNorm -> f16
__launch_bounds__(256)
__global__ void ln_kernel(const float* __restrict__ x, const float* __restrict__ g,
                          const float* __restrict__ b, f16* __restrict__ y) {
    int row = blockIdx.x;
    int tid = threadIdx.x;
    const float* xr = x + (size_t)row * N_EMB;
    float4 v = *(const float4*)(xr + tid * 4);
    float s  = v.x + v.y + v.z + v.w;
    float sq = v.x * v.x + v.y * v.y + v.z * v.z + v.w * v.w;
    #pragma unroll
    for (int off = 32; off > 0; off >>= 1) {
        s  += __shfl_down(s, off);
        sq += __shfl_down(sq, off);
    }
    __shared__ float ws_[4], wq_[4];
    __shared__ float mean_s, rstd_s;
    int lane = tid & 63, wid = tid >> 6;
    if (lane == 0) { ws_[wid] = s; wq_[wid] = sq; }
    __syncthreads();
    if (tid == 0) {
        float st = ws_[0] + ws_[1] + ws_[2] + ws_[3];
        float qt = wq_[0] + wq_[1] + wq_[2] + wq_[3];
        float mu = st * (1.0f / N_EMB);
        float var = qt * (1.0f / N_EMB) - mu * mu;
        mean_s = mu;
        rstd_s = rsqrtf(var + 1e-5f);
    }
    __syncthreads();
    float mu = mean_s, r = rstd_s;
    float4 gv = *(const float4*)(g + tid * 4);
    float4 bv = *(const float4*)(b + tid * 4);
    f16x4 o;
    o.x = (f16)((v.x - mu) * r * gv.x + bv.x);
    o.y = (f16)((v.y - mu) * r * gv.y + bv.y);
    o.z = (f16)((v.z - mu) * r * gv.z + bv.z);
    o.w = (f16)((v.w - mu) * r * gv.w + bv.w);
    *(f16x4*)(y + (size_t)row * N_EMB + tid * 4) = o;
}

// ---------------------------------------------------------------- GEMM 128x128
// r5 kernel: dbuf LDS, single barrier per k-iter, async prefetch.
// EPI: 0 f32 | 1 f32 + f32 residual | 2 gelu->f16 | 3 qkv split
template <int EPI>
__launch_bounds__(256)
__global__ void gemm_f16(const f16* __restrict__ A, const f16* __restrict__ Bt,
                         const float* __restrict__ bias, const float* __restrict__ res,
                         float* __restrict__ Cf, f16* __restrict__ Ch,
                         f16* __restrict__ vT, int K, int N) {
    __shared__ f16 As[2][128 * 32];
    __shared__ f16 Bs[2][128 * 32];
    int tid = threadIdx.x;
    int lane = tid & 63, wave = tid >> 6;
    int wr = wave >> 1, wc = wave & 1;
    int quad = lane >> 4, l16 = lane & 15;
    int m0 = blockIdx.y * 128, n0 = blockIdx.x * 128;

    int r0 = tid >> 2;
    int s0 = (tid & 3) * 8;
    const f16* paA0 = A  + (size_t)(m0 + r0) * K + s0;
    const f16* paA1 = A  + (size_t)(m0 + r0 + 64) * K + s0;
    const f16* paB0 = Bt + (size_t)(n0 + r0) * K + s0;
    const f16* paB1 = Bt + (size_t)(n0 + r0 + 64) * K + s0;
    char* dA0 = (char*)As + (size_t)tid * 16;
    char* dA1 = (char*)As + (size_t)(256 + tid) * 16;
    char* dB0 = (char*)Bs + (size_t)tid * 16;
    char* dB1 = (char*)Bs + (size_t)(256 + tid) * 16;

    async16(dA0, paA0);
    async16(dA1, paA1);
    async16(dB0, paB0);
    async16(dB1, paB1);

    f32x4 acc[4][4] = {};
    int p = 0;
    for (int k0 = 0; k0 < K; k0 += 32, p ^= 1) {
        __syncthreads();
        if (k0 + 32 < K) {
            int koff = k0 + 32;
            async16(dA0 + (p ^ 1) * 8192, paA0 + koff);
            async16(dA1 + (p ^ 1) * 8192, paA1 + koff);
            async16(dB0 + (p ^ 1) * 8192, paB0 + koff);
            async16(dB1 + (p ^ 1) * 8192, paB1 + koff);
        }
        const f16* as = As[p];
        const f16* bs = Bs[p];
        f16x8 af[4], bf[4];
        #pragma unroll
        for (int i = 0; i < 4; i++)
            af[i] = *(const f16x8*)&as[(wr * 64 + i * 16 + l16) * 32 + quad * 8];
        #pragma unroll
        for (int j = 0; j < 4; j++)
            bf[j] = *(const f16x8*)&bs[(wc * 64 + j * 16 + l16) * 32 + quad * 8];
        #pragma unroll
        for (int i = 0; i < 4; i++)
            #pragma unroll
            for (int j = 0; j < 4; j++)
                acc[i][j] = __builtin_amdgcn_mfma_f32_16x16x32_f16(
                    af[i], bf[j], acc[i][j], 0, 0, 0);
    }

    #pragma unroll
    for (int i = 0; i < 4; i++) {
        int row0 = m0 + wr * 64 + i * 16 + quad * 4;
        #pragma unroll
        for (int j = 0; j < 4; j++) {
            int col = n0 + wc * 64 + j * 16 + l16;
            float bb = bias[col];
            if (EPI == 3) {
                if (n0 < 2048) {
                    #pragma unroll
                    for (int r = 0; r < 4; r++)
                        Ch[(size_t)(row0 + r) * 2048 + col] = (f16)(acc[i][j][r] + bb);
                } else {
                    int hh = (col - 2048) >> 6, dd = col & 63;
                    int bb_ = row0 >> 11, t0 = row0 & 2047;
                    f16x4 pk;
                    pk.x = (f16)(acc[i][j][0] + bb);
                    pk.y = (f16)(acc[i][j][1] + bb);
                    pk.z = (f16)(acc[i][j][2] + bb);
                    pk.w = (f16)(acc[i][j][3] + bb);
                    *(f16x4*)(vT + ((size_t)(bb_ * 16 + hh) * 64 + dd) * 2048 + t0) = pk;
                }
            } else {
                #pragma unroll
                for (int r = 0; r < 4; r++) {
                    size_t idx = (size_t)(row0 + r) * N + col;
                    float v = acc[i][j][r] + bb;
                    if (EPI == 1) v += res[idx];
                    if (EPI == 2) Ch[idx] = (f16)gelu_tanh(v);
                    else          Cf[idx] = v;
                }
            }
        }
    }
}

// ---------------------------------------------------------------- flash (no barriers)
// 256 thr = 4 independent waves; wave w owns q rows [q0+w*32, q0+w*32+32).
// K frags: direct global loads (A-layout = qk rows). V frags: direct global
// loads (B-layout = vT rows). P: per-wave LDS round-trip (C->A layout) with
// explicit LDS_FENCE() around the store burst (cross-lane RAW/WAR ordering —
// the compiler will not emit these waits itself).
__launch_bounds__(256)
__global__ void flash_kernel(const f16* __restrict__ qk, const f16* __restrict__ vT,
                             f16* __restrict__ y) {
    __shared__ __align__(16) f16 PsAll[4][32 * 136];
    int tid = threadIdx.x;
    int lane = tid & 63, w = tid >> 6;
    int quad = lane >> 4, l16 = lane & 15;
    f16* Ps = PsAll[w];

    int qt = 15 - blockIdx.x;                  // long blocks first
    int bh = blockIdx.y;
    int b = bh >> 4, h = bh & 15;
    int q0 = qt * 128;
    const f16* kbase = qk + (size_t)b * T_SEQ * 2048 + 1024 + h * 64;
    const f16* vbase = vT + (size_t)bh * 64 * 2048;

    // Q B-frags, pre-scaled by 0.125*log2(e) (exp2 softmax)
    const f16 qsc = (f16)0.1803368801f;
    f16x8 qf[2][2];
    #pragma unroll
    for (int qn = 0; qn < 2; qn++) {
        int q = q0 + w * 32 + qn * 16 + l16;
        #pragma unroll
        for (int dblk = 0; dblk < 2; dblk++) {
            f16x8 t = *(const f16x8*)(qk + ((size_t)b * T_SEQ + q) * 2048 +
                                      h * 64 + dblk * 32 + quad * 8);
            #pragma unroll
            for (int e = 0; e < 8; e++) t[e] = t[e] * qsc;
            qf[qn][dblk] = t;
        }
    }

    float m_r[2] = {-INFINITY, -INFINITY};
    float l_r[2] = {0.0f, 0.0f};
    f32x4 Oacc[2][4] = {};

    for (int jt = 0; jt <= qt; jt++) {
        int j0 = jt * 128;

        // S^T = K . Q^T ; K A-frags straight from global (16B/lane each)
        f32x4 S[8][2];
        #pragma unroll
        for (int jm = 0; jm < 8; jm++) {
            const f16* krow = kbase + (size_t)(j0 + jm * 16 + l16) * 2048 + quad * 8;
            f16x8 kf0 = *(const f16x8*)krow;
            f16x8 kf1 = *(const f16x8*)(krow + 32);
            #pragma unroll
            for (int qn = 0; qn < 2; qn++) {
                f32x4 s = {};
                s = __builtin_amdgcn_mfma_f32_16x16x32_f16(kf0, qf[qn][0], s, 0, 0, 0);
                s = __builtin_amdgcn_mfma_f32_16x16x32_f16(kf1, qf[qn][1], s, 0, 0, 0);
                S[jm][qn] = s;
            }
        }

        if (jt == qt) {  // diagonal mask: j > q
            #pragma unroll
            for (int jm = 0; jm < 8; jm++)
                #pragma unroll
                for (int qn = 0; qn < 2; qn++)
                    #pragma unroll
                    for (int r = 0; r < 4; r++) {
                        int jl = jm * 16 + quad * 4 + r;
                        int ql = w * 32 + qn * 16 + l16;
                        if (jl > ql) S[jm][qn][r] = -1e30f;
                    }
        }

        // online softmax (exp2); state per q col = l16, replicated across quads
        float alpha[2];
        #pragma unroll
        for (int qn = 0; qn < 2; qn++) {
            float tmax = -INFINITY;
            #pragma unroll
            for (int jm = 0; jm < 8; jm++)
                #pragma unroll
                for (int r = 0; r < 4; r++)
                    tmax = fmaxf(tmax, S[jm][qn][r]);
            tmax = fmaxf(tmax, __shfl_xor(tmax, 16));
            tmax = fmaxf(tmax, __shfl_xor(tmax, 32));
            float mnew = fmaxf(m_r[qn], tmax);
            alpha[qn] = exp2f(m_r[qn] - mnew);
            m_r[qn] = mnew;
            float rsum = 0.0f;
            #pragma unroll
            for (int jm = 0; jm < 8; jm++)
                #pragma unroll
                for (int r = 0; r < 4; r++) {
                    float pp = exp2f(S[jm][qn][r] - mnew);
                    S[jm][qn][r] = pp;
                    rsum += pp;
                }
            rsum += __shfl_xor(rsum, 16);
            rsum += __shfl_xor(rsum, 32);
            l_r[qn] = l_r[qn] * alpha[qn] + rsum;
        }

        // WAR fence: previous iteration's P-loads must complete before we
        // overwrite Ps (cross-lane; compiler won't order this itself).
        LDS_FENCE();

        // P -> per-wave LDS (C-layout out, A-layout in)
        #pragma unroll
        for (int jm = 0; jm < 8; jm++)
            #pragma unroll
            for (int qn = 0; qn < 2; qn++) {
                f16x4 pk;
                pk.x = (f16)S[jm][qn][0];
                pk.y = (f16)S[jm][qn][1];
                pk.z = (f16)S[jm][qn][2];
                pk.w = (f16)S[jm][qn][3];
                *(f16x4*)(Ps + (size_t)(qn * 16 + l16) * 136 + jm * 16 + quad * 4) = pk;
            }

        // RAW fence: P stores visible to all lanes before the A-frag reads.
        LDS_FENCE();

        // rescale O by alpha (O rows are q = quad*4+r)
        float aPV[2][4];
        #pragma unroll
        for (int m = 0; m < 2; m++)
            #pragma unroll
            for (int r = 0; r < 4; r++)
                aPV[m][r] = __shfl(alpha[m], quad * 20 + r);
        #pragma unroll
        for (int m = 0; m < 2; m++)
            #pragma unroll
            for (int n = 0; n < 4; n++)
                #pragma unroll
                for (int r = 0; r < 4; r++)
                    Oacc[m][n][r] *= aPV[m][r];

        // O += P V ; V B-frags straight from vT (16B/lane each)
        #pragma unroll
        for (int kblk = 0; kblk < 4; kblk++) {
            f16x8 pf[2];
            #pragma unroll
            for (int m = 0; m < 2; m++)
                pf[m] = *(const f16x8*)(Ps + (size_t)(m * 16 + l16) * 136 +
                                        kblk * 32 + quad * 8);
            f16x8 vf[4];
            #pragma unroll
            for (int n = 0; n < 4; n++)
                vf[n] = *(const f16x8*)(vbase + (size_t)(n * 16 + l16) * 2048 +
                                        j0 + kblk * 32 + quad * 8);
            #pragma unroll
            for (int m = 0; m < 2; m++)
                #pragma unroll
                for (int n = 0; n < 4; n++)
                    Oacc[m][n] = __builtin_amdgcn_mfma_f32_16x16x32_f16(
                        pf[m], vf[n], Oacc[m][n], 0, 0, 0);
        }
    }

    // epilogue: O / l -> ybuf [B,T,C] f16
    #pragma unroll
    for (int m = 0; m < 2; m++) {
        float lPV[4];
        #pragma unroll
        for (int r = 0; r < 4; r++)
            lPV[r] = 1.0f / __shfl(l_r[m], quad * 20 + r);
        #pragma unroll
        for (int n = 0; n < 4; n++) {
            #pragma unroll
            for (int r = 0; r < 4; r++) {
                int q = q0 + w * 32 + m * 16 + quad * 4 + r;
                y[(size_t)(b * T_SEQ + q) * N_EMB + h * 64 + n * 16 + l16] =
                    (f16)(Oacc[m][n][r] * lPV[r]);
            }
        }
    }
}

// ---------------------------------------------------------------- launch
extern "C" void kernel_launch(void* const* d_in, const int* in_sizes, int n_in,
                              void* d_out, int out_size, void* d_ws, size_t ws_size,
                              hipStream_t stream) {
    const float* x      = (const float*)d_in[0];
    const float* ln1_g  = (const float*)d_in[1];
    const float* ln1_b  = (const float*)d_in[2];
    const float* w_attn = (const float*)d_in[3];
    const float* b_attn = (const float*)d_in[4];
    const float* w_proj = (const float*)d_in[5];
    const float* b_proj = (const float*)d_in[6];
    const float* ln2_g  = (const float*)d_in[7];
    const float* ln2_b  = (const float*)d_in[8];
    const float* w_fc   = (const float*)d_in[9];
    const float* b_fc   = (const float*)d_in[10];
    const float* w_fc2  = (const float*)d_in[11];
    const float* b_fc2  = (const float*)d_in[12];
    float* out = (float*)d_out;

    const size_t MB = 1024 * 1024;
    char* ws = (char*)d_ws;
    f16*   lnbuf = (f16*)ws;                        // 16 MB
    f16*   qkbuf = (f16*)(ws + 16 * MB);            // 32 MB: [M][2048] Q|K
    f16*   vTbuf = (f16*)(ws + 48 * MB);            // 16 MB: [b][h][d][t]
    f16*   ybuf  = (f16*)(ws + 64 * MB);            // 16 MB
    f16*   h     = (f16*)(ws + 80 * MB);            // 64 MB
    f16*   wT    = (f16*)(ws + 144 * MB);           // 26 MB
    f16* wT_attn = wT;
    f16* wT_proj = wT_attn + (size_t)3072 * 1024;
    f16* wT_fc   = wT_proj + (size_t)1024 * 1024;
    f16* wT_fc2  = wT_fc   + (size_t)1024 * 4096;

    wconv_kernel<<<dim3(3072 / 32, 1024 / 32), 256, 0, stream>>>(w_attn, wT_attn, 1024, 3072);
    wconv_kernel<<<dim3(1024 / 32, 1024 / 32), 256, 0, stream>>>(w_proj, wT_proj, 1024, 1024);
    wconv_kernel<<<dim3(4096 / 32, 1024 / 32), 256, 0, stream>>>(w_fc,   wT_fc,   1024, 4096);
    wconv_kernel<<<dim3(1024 / 32, 4096 / 32), 256, 0, stream>>>(w_fc2,  wT_fc2,  4096, 1024);

    ln_kernel<<<M_ROWS, 256, 0, stream>>>(x, ln1_g, ln1_b, lnbuf);
    gemm_f16<3><<<dim3(3072 / 128, M_ROWS / 128), 256, 0, stream>>>(
        lnbuf, wT_attn, b_attn, nullptr, nullptr, qkbuf, vTbuf, 1024, 3072);
    flash_kernel<<<dim3(16, 64), 256, 0, stream>>>(qkbuf, vTbuf, ybuf);
    gemm_f16<1><<<dim3(1024 / 128, M_ROWS / 128), 256, 0, stream>>>(
        ybuf, wT_proj, b_proj, x, out, nullptr, nullptr, 1024, 1024);
    ln_kernel<<<M_ROWS, 256, 0, stream>>>(out, ln2_g, ln2_b, lnbuf);
    gemm_f16<2><<<dim3(4096 / 128, M_ROWS / 128), 256, 0, stream>>>(
        lnbuf, wT_fc, b_fc, nullptr, nullptr, h, nullptr, 1024, 4096);
    gemm_f16<1><<<dim3(1024 / 128, M_ROWS / 128), 256, 0, stream>>>(
        h, wT_fc2, b_fc2, out, out, nullptr, nullptr, 4096, 1024);
}

// Round 9
// 678.276 us; speedup vs baseline: 1.1415x; 1.1415x over previous
//
#include <hip/hip_runtime.h>
#include <math.h>

// Round 9: flash = r5's proven 2-barrier staged structure, with Ps halved
// (32x72/wave, fence-protected halves) to cut LDS 67.5->50KB => 3 blocks/CU
// (was 2). r5 profile is drain-latency-bound; inter-block overlap is the
// hiding mechanism, so +50% residency is the direct lever. exp2 softmax kept.
// GEMMs/LN/wconv: identical to r5 (the 576us config).
//
// ws: [0,16M) lnbuf | [16,48M) qk | [48,64M) vT | [64,80M) ybuf
//     [80,144M) h | [144,170M) wT

#define M_ROWS 8192
#define T_SEQ 2048
#define N_EMB 1024
#define N_HEADS 16
#define HEAD_D 64

typedef _Float16 f16;
typedef __attribute__((ext_vector_type(8))) _Float16 f16x8;
typedef __attribute__((ext_vector_type(4))) _Float16 f16x4;
typedef __attribute__((ext_vector_type(4))) float f32x4;

// wave-local LDS fence: cross-lane LDS RAW/WAR ordering (compiler only tracks
// per-lane register deps — r7 post-mortem).
#define LDS_FENCE() asm volatile("s_waitcnt lgkmcnt(0)" ::: "memory")

__device__ __forceinline__ void async16(void* lds, const void* g) {
    __builtin_amdgcn_global_load_lds(
        (const __attribute__((address_space(1))) unsigned int*)g,
        (__attribute__((address_space(3))) unsigned int*)lds, 16, 0, 0);
}

__device__ __forceinline__ float gelu_tanh(float v) {
    float u = 0.7978845608028654f * (v + 0.044715f * v * v * v);
    float e = __expf(2.0f * u);
    float t = 1.0f - 2.0f / (e + 1.0f);
    return 0.5f * v * (1.0f + t);
}

// ---------------------------------------------------------------- weight convert
__launch_bounds__(256)
__global__ void wconv_kernel(const float* __restrict__ W, f16* __restrict__ WT,
                             int K, int N) {
    __shared__ float t[32][33];
    int tx = threadIdx.x & 31, ty = threadIdx.x >> 5;
    int n0 = blockIdx.x * 32, k0 = blockIdx.y * 32;
    #pragma unroll
    for (int r = 0; r < 4; r++)
        t[ty * 4 + r][tx] = W[(size_t)(k0 + ty * 4 + r) * N + n0 + tx];
    __syncthreads();
    #pragma unroll
    for (int r = 0; r < 4; r++)
        WT[(size_t)(n0 + ty * 4 + r) * K + k0 + tx] = (f16)t[tx][ty * 4 + r];
}

// ---------------------------------------------------------------- LayerNorm -> f16
__launch_bounds__(256)
__global__ void ln_kernel(const float* __restrict__ x, const float* __restrict__ g,
                          const float* __restrict__ b, f16* __restrict__ y) {
    int row = blockIdx.x;
    int tid = threadIdx.x;
    const float* xr = x + (size_t)row * N_EMB;
    float4 v = *(const float4*)(xr + tid * 4);
    float s  = v.x + v.y + v.z + v.w;
    float sq = v.x * v.x + v.y * v.y + v.z * v.z + v.w * v.w;
    #pragma unroll
    for (int off = 32; off > 0; off >>= 1) {
        s  += __shfl_down(s, off);
        sq += __shfl_down(sq, off);
    }
    __shared__ float ws_[4], wq_[4];
    __shared__ float mean_s, rstd_s;
    int lane = tid & 63, wid = tid >> 6;
    if (lane == 0) { ws_[wid] = s; wq_[wid] = sq; }
    __syncthreads();
    if (tid == 0) {
        float st = ws_[0] + ws_[1] + ws_[2] + ws_[3];
        float qt = wq_[0] + wq_[1] + wq_[2] + wq_[3];
        float mu = st * (1.0f / N_EMB);
        float var = qt * (1.0f / N_EMB) - mu * mu;
        mean_s = mu;
        rstd_s = rsqrtf(var + 1e-5f);
    }
    __syncthreads();
    float mu = mean_s, r = rstd_s;
    float4 gv = *(const float4*)(g + tid * 4);
    float4 bv = *(const float4*)(b + tid * 4);
    f16x4 o;
    o.x = (f16)((v.x - mu) * r * gv.x + bv.x);
    o.y = (f16)((v.y - mu) * r * gv.y + bv.y);
    o.z = (f16)((v.z - mu) * r * gv.z + bv.z);
    o.w = (f16)((v.w - mu) * r * gv.w + bv.w);
    *(f16x4*)(y + (size_t)row * N_EMB + tid * 4) = o;
}

// ---------------------------------------------------------------- GEMM 128x128
// r5 kernel: dbuf LDS, single barrier per k-iter, async prefetch.
// EPI: 0 f32 | 1 f32 + f32 residual | 2 gelu->f16 | 3 qkv split
template <int EPI>
__launch_bounds__(256)
__global__ void gemm_f16(const f16* __restrict__ A, const f16* __restrict__ Bt,
                         const float* __restrict__ bias, const float* __restrict__ res,
                         float* __restrict__ Cf, f16* __restrict__ Ch,
                         f16* __restrict__ vT, int K, int N) {
    __shared__ f16 As[2][128 * 32];
    __shared__ f16 Bs[2][128 * 32];
    int tid = threadIdx.x;
    int lane = tid & 63, wave = tid >> 6;
    int wr = wave >> 1, wc = wave & 1;
    int quad = lane >> 4, l16 = lane & 15;
    int m0 = blockIdx.y * 128, n0 = blockIdx.x * 128;

    int r0 = tid >> 2;
    int s0 = (tid & 3) * 8;
    const f16* paA0 = A  + (size_t)(m0 + r0) * K + s0;
    const f16* paA1 = A  + (size_t)(m0 + r0 + 64) * K + s0;
    const f16* paB0 = Bt + (size_t)(n0 + r0) * K + s0;
    const f16* paB1 = Bt + (size_t)(n0 + r0 + 64) * K + s0;
    char* dA0 = (char*)As + (size_t)tid * 16;
    char* dA1 = (char*)As + (size_t)(256 + tid) * 16;
    char* dB0 = (char*)Bs + (size_t)tid * 16;
    char* dB1 = (char*)Bs + (size_t)(256 + tid) * 16;

    async16(dA0, paA0);
    async16(dA1, paA1);
    async16(dB0, paB0);
    async16(dB1, paB1);

    f32x4 acc[4][4] = {};
    int p = 0;
    for (int k0 = 0; k0 < K; k0 += 32, p ^= 1) {
        __syncthreads();
        if (k0 + 32 < K) {
            int koff = k0 + 32;
            async16(dA0 + (p ^ 1) * 8192, paA0 + koff);
            async16(dA1 + (p ^ 1) * 8192, paA1 + koff);
            async16(dB0 + (p ^ 1) * 8192, paB0 + koff);
            async16(dB1 + (p ^ 1) * 8192, paB1 + koff);
        }
        const f16* as = As[p];
        const f16* bs = Bs[p];
        f16x8 af[4], bf[4];
        #pragma unroll
        for (int i = 0; i < 4; i++)
            af[i] = *(const f16x8*)&as[(wr * 64 + i * 16 + l16) * 32 + quad * 8];
        #pragma unroll
        for (int j = 0; j < 4; j++)
            bf[j] = *(const f16x8*)&bs[(wc * 64 + j * 16 + l16) * 32 + quad * 8];
        #pragma unroll
        for (int i = 0; i < 4; i++)
            #pragma unroll
            for (int j = 0; j < 4; j++)
                acc[i][j] = __builtin_amdgcn_mfma_f32_16x16x32_f16(
                    af[i], bf[j], acc[i][j], 0, 0, 0);
    }

    #pragma unroll
    for (int i = 0; i < 4; i++) {
        int row0 = m0 + wr * 64 + i * 16 + quad * 4;
        #pragma unroll
        for (int j = 0; j < 4; j++) {
            int col = n0 + wc * 64 + j * 16 + l16;
            float bb = bias[col];
            if (EPI == 3) {
                if (n0 < 2048) {
                    #pragma unroll
                    for (int r = 0; r < 4; r++)
                        Ch[(size_t)(row0 + r) * 2048 + col] = (f16)(acc[i][j][r] + bb);
                } else {
                    int hh = (col - 2048) >> 6, dd = col & 63;
                    int bb_ = row0 >> 11, t0 = row0 & 2047;
                    f16x4 pk;
                    pk.x = (f16)(acc[i][j][0] + bb);
                    pk.y = (f16)(acc[i][j][1] + bb);
                    pk.z = (f16)(acc[i][j][2] + bb);
                    pk.w = (f16)(acc[i][j][3] + bb);
                    *(f16x4*)(vT + ((size_t)(bb_ * 16 + hh) * 64 + dd) * 2048 + t0) = pk;
                }
            } else {
                #pragma unroll
                for (int r = 0; r < 4; r++) {
                    size_t idx = (size_t)(row0 + r) * N + col;
                    float v = acc[i][j][r] + bb;
                    if (EPI == 1) v += res[idx];
                    if (EPI == 2) Ch[idx] = (f16)gelu_tanh(v);
                    else          Cf[idx] = v;
                }
            }
        }
    }
}

// ---------------------------------------------------------------- MFMA flash
// r5 structure: 256 thr = 4 waves, 128 q/block (wave owns 32), 128-j tiles,
// K/V staged via global_load_lds + 2 barriers per iter. Ps halved to 32x72
// per wave (two 64-j halves, LDS_FENCE-protected). exp2 softmax.
// LDS: 16K (Ks) + 16K (Vs) + 18K (Ps) = 50KB -> 3 blocks/CU.
__launch_bounds__(256)
__global__ void flash_kernel(const f16* __restrict__ qk, const f16* __restrict__ vT,
                             f16* __restrict__ y) {
    __shared__ __align__(16) char smem[51200];
    f16* Ks = (f16*)smem;                      // [128 j][8 g of 8 d], g^=(j&7)
    f16* Vs = (f16*)(smem + 16384);            // [64 d][16 g of 8 j], g^=(d&7)
    int tid = threadIdx.x;
    int lane = tid & 63, w = tid >> 6;
    int quad = lane >> 4, l16 = lane & 15;
    f16* Ps = (f16*)(smem + 32768 + w * 4608); // per-wave [32 q][72], one 64-j half

    int qt = 15 - blockIdx.x;                  // long blocks first
    int bh = blockIdx.y;
    int b = bh >> 4, h = bh & 15;
    int q0 = qt * 128;
    const size_t qkrow = (size_t)b * T_SEQ * 2048;

    // Q B-frags, pre-scaled by 0.125*log2(e) (exp2 softmax)
    const f16 qsc = (f16)0.1803368801f;
    f16x8 qf[2][2];
    #pragma unroll
    for (int qn = 0; qn < 2; qn++) {
        int q = q0 + w * 32 + qn * 16 + l16;
        #pragma unroll
        for (int dblk = 0; dblk < 2; dblk++) {
            f16x8 t = *(const f16x8*)(qk + qkrow + (size_t)q * 2048 +
                                      h * 64 + dblk * 32 + quad * 8);
            #pragma unroll
            for (int e = 0; e < 8; e++) t[e] = t[e] * qsc;
            qf[qn][dblk] = t;
        }
    }

    float m_r[2] = {-INFINITY, -INFINITY};
    float l_r[2] = {0.0f, 0.0f};
    f32x4 Oacc[2][4] = {};

    for (int jt = 0; jt <= qt; jt++) {
        int j0 = jt * 128;
        __syncthreads();   // prev readers of Ks/Vs done
        #pragma unroll
        for (int i = 0; i < 4; i++) {
            int L = i * 256 + tid;
            int j = L >> 3, g1 = L & 7;
            int g = g1 ^ (j & 7);
            async16((char*)Ks + (size_t)L * 16,
                    qk + qkrow + (size_t)(j0 + j) * 2048 + 1024 + h * 64 + g * 8);
        }
        #pragma unroll
        for (int i = 0; i < 4; i++) {
            int L = i * 256 + tid;
            int d = L >> 4, g1 = L & 15;
            int g = (g1 & 8) | ((g1 ^ d) & 7);
            async16((char*)Vs + (size_t)L * 16,
                    vT + ((size_t)bh * 64 + d) * 2048 + j0 + g * 8);
        }
        __syncthreads();   // DMA drained: Ks/Vs ready

        // S^T = K . Q^T
        f32x4 S[8][2];
        #pragma unroll
        for (int jm = 0; jm < 8; jm++) {
            f16x8 kf[2];
            #pragma unroll
            for (int dblk = 0; dblk < 2; dblk++) {
                int j = jm * 16 + l16;
                int g = (dblk * 4 + quad) ^ (j & 7);
                kf[dblk] = *(const f16x8*)(Ks + (size_t)(j * 8 + g) * 8);
            }
            #pragma unroll
            for (int qn = 0; qn < 2; qn++) {
                f32x4 s = {};
                s = __builtin_amdgcn_mfma_f32_16x16x32_f16(kf[0], qf[qn][0], s, 0, 0, 0);
                s = __builtin_amdgcn_mfma_f32_16x16x32_f16(kf[1], qf[qn][1], s, 0, 0, 0);
                S[jm][qn] = s;
            }
        }

        if (jt == qt) {  // diagonal mask: j > q (tile-local)
            #pragma unroll
            for (int jm = 0; jm < 8; jm++)
                #pragma unroll
                for (int qn = 0; qn < 2; qn++)
                    #pragma unroll
                    for (int r = 0; r < 4; r++) {
                        int jl = jm * 16 + quad * 4 + r;
                        int ql = w * 32 + qn * 16 + l16;
                        if (jl > ql) S[jm][qn][r] = -1e30f;
                    }
        }

        // online softmax (exp2 domain)
        float alpha[2];
        #pragma unroll
        for (int qn = 0; qn < 2; qn++) {
            float tmax = -INFINITY;
            #pragma unroll
            for (int jm = 0; jm < 8; jm++)
                #pragma unroll
                for (int r = 0; r < 4; r++)
                    tmax = fmaxf(tmax, S[jm][qn][r]);
            tmax = fmaxf(tmax, __shfl_xor(tmax, 16));
            tmax = fmaxf(tmax, __shfl_xor(tmax, 32));
            float mnew = fmaxf(m_r[qn], tmax);
            alpha[qn] = exp2f(m_r[qn] - mnew);
            m_r[qn] = mnew;
            float rsum = 0.0f;
            #pragma unroll
            for (int jm = 0; jm < 8; jm++)
                #pragma unroll
                for (int r = 0; r < 4; r++) {
                    float pp = exp2f(S[jm][qn][r] - mnew);
                    S[jm][qn][r] = pp;
                    rsum += pp;
                }
            rsum += __shfl_xor(rsum, 16);
            rsum += __shfl_xor(rsum, 32);
            l_r[qn] = l_r[qn] * alpha[qn] + rsum;
        }

        // rescale O by alpha
        float aPV[2][4];
        #pragma unroll
        for (int m = 0; m < 2; m++)
            #pragma unroll
            for (int r = 0; r < 4; r++)
                aPV[m][r] = __shfl(alpha[m], quad * 20 + r);
        #pragma unroll
        for (int m = 0; m < 2; m++)
            #pragma unroll
            for (int n = 0; n < 4; n++)
                #pragma unroll
                for (int r = 0; r < 4; r++)
                    Oacc[m][n][r] *= aPV[m][r];

        // ---- P half 0 (j 0..63): store, fence, PV kblk 0..1
        #pragma unroll
        for (int jm = 0; jm < 4; jm++)
            #pragma unroll
            for (int qn = 0; qn < 2; qn++) {
                f16x4 pk;
                pk.x = (f16)S[jm][qn][0];
                pk.y = (f16)S[jm][qn][1];
                pk.z = (f16)S[jm][qn][2];
                pk.w = (f16)S[jm][qn][3];
                *(f16x4*)(Ps + (size_t)(qn * 16 + l16) * 72 + jm * 16 + quad * 4) = pk;
            }
        LDS_FENCE();   // RAW: half0 visible to all lanes
        #pragma unroll
        for (int kblk = 0; kblk < 2; kblk++) {
            f16x8 pf[2];
            #pragma unroll
            for (int m = 0; m < 2; m++)
                pf[m] = *(const f16x8*)(Ps + (size_t)(m * 16 + l16) * 72 +
                                        kblk * 32 + quad * 8);
            f16x8 vf[4];
            #pragma unroll
            for (int n = 0; n < 4; n++) {
                int d = n * 16 + l16;
                int g = kblk * 4 + quad;
                int gs = (g & 8) | ((g ^ d) & 7);
                vf[n] = *(const f16x8*)(Vs + (size_t)(d * 16 + gs) * 8);
            }
            #pragma unroll
            for (int m = 0; m < 2; m++)
                #pragma unroll
                for (int n = 0; n < 4; n++)
                    Oacc[m][n] = __builtin_amdgcn_mfma_f32_16x16x32_f16(
                        pf[m], vf[n], Oacc[m][n], 0, 0, 0);
        }
        LDS_FENCE();   // WAR: half0 reads done before overwrite

        // ---- P half 1 (j 64..127): store, fence, PV kblk 2..3
        #pragma unroll
        for (int jm = 4; jm < 8; jm++)
            #pragma unroll
            for (int qn = 0; qn < 2; qn++) {
                f16x4 pk;
                pk.x = (f16)S[jm][qn][0];
                pk.y = (f16)S[jm][qn][1];
                pk.z = (f16)S[jm][qn][2];
                pk.w = (f16)S[jm][qn][3];
                *(f16x4*)(Ps + (size_t)(qn * 16 + l16) * 72 + (jm - 4) * 16 + quad * 4) = pk;
            }
        LDS_FENCE();   // RAW: half1 visible
        #pragma unroll
        for (int kblk = 2; kblk < 4; kblk++) {
            f16x8 pf[2];
            #pragma unroll
            for (int m = 0; m < 2; m++)
                pf[m] = *(const f16x8*)(Ps + (size_t)(m * 16 + l16) * 72 +
                                        (kblk - 2) * 32 + quad * 8);
            f16x8 vf[4];
            #pragma unroll
            for (int n = 0; n < 4; n++) {
                int d = n * 16 + l16;
                int g = kblk * 4 + quad;
                int gs = (g & 8) | ((g ^ d) & 7);
                vf[n] = *(const f16x8*)(Vs + (size_t)(d * 16 + gs) * 8);
            }
            #pragma unroll
            for (int m = 0; m < 2; m++)
                #pragma unroll
                for (int n = 0; n < 4; n++)
                    Oacc[m][n] = __builtin_amdgcn_mfma_f32_16x16x32_f16(
                        pf[m], vf[n], Oacc[m][n], 0, 0, 0);
        }
    }

    // epilogue: O / l -> ybuf [B,T,C] f16
    #pragma unroll
    for (int m = 0; m < 2; m++) {
        float lPV[4];
        #pragma unroll
        for (int r = 0; r < 4; r++)
            lPV[r] = 1.0f / __shfl(l_r[m], quad * 20 + r);
        #pragma unroll
        for (int n = 0; n < 4; n++) {
            #pragma unroll
            for (int r = 0; r < 4; r++) {
                int q = q0 + w * 32 + m * 16 + quad * 4 + r;
                y[(size_t)(b * T_SEQ + q) * N_EMB + h * 64 + n * 16 + l16] =
                    (f16)(Oacc[m][n][r] * lPV[r]);
            }
        }
    }
}

// ---------------------------------------------------------------- launch
extern "C" void kernel_launch(void* const* d_in, const int* in_sizes, int n_in,
                              void* d_out, int out_size, void* d_ws, size_t ws_size,
                              hipStream_t stream) {
    const float* x      = (const float*)d_in[0];
    const float* ln1_g  = (const float*)d_in[1];
    const float* ln1_b  = (const float*)d_in[2];
    const float* w_attn = (const float*)d_in[3];
    const float* b_attn = (const float*)d_in[4];
    const float* w_proj = (const float*)d_in[5];
    const float* b_proj = (const float*)d_in[6];
    const float* ln2_g  = (const float*)d_in[7];
    const float* ln2_b  = (const float*)d_in[8];
    const float* w_fc   = (const float*)d_in[9];
    const float* b_fc   = (const float*)d_in[10];
    const float* w_fc2  = (const float*)d_in[11];
    const float* b_fc2  = (const float*)d_in[12];
    float* out = (float*)d_out;

    const size_t MB = 1024 * 1024;
    char* ws = (char*)d_ws;
    f16*   lnbuf = (f16*)ws;                        // 16 MB
    f16*   qkbuf = (f16*)(ws + 16 * MB);            // 32 MB: [M][2048] Q|K
    f16*   vTbuf = (f16*)(ws + 48 * MB);            // 16 MB: [b][h][d][t]
    f16*   ybuf  = (f16*)(ws + 64 * MB);            // 16 MB
    f16*   h     = (f16*)(ws + 80 * MB);            // 64 MB
    f16*   wT    = (f16*)(ws + 144 * MB);           // 26 MB
    f16* wT_attn = wT;
    f16* wT_proj = wT_attn + (size_t)3072 * 1024;
    f16* wT_fc   = wT_proj + (size_t)1024 * 1024;
    f16* wT_fc2  = wT_fc   + (size_t)1024 * 4096;

    wconv_kernel<<<dim3(3072 / 32, 1024 / 32), 256, 0, stream>>>(w_attn, wT_attn, 1024, 3072);
    wconv_kernel<<<dim3(1024 / 32, 1024 / 32), 256, 0, stream>>>(w_proj, wT_proj, 1024, 1024);
    wconv_kernel<<<dim3(4096 / 32, 1024 / 32), 256, 0, stream>>>(w_fc,   wT_fc,   1024, 4096);
    wconv_kernel<<<dim3(1024 / 32, 4096 / 32), 256, 0, stream>>>(w_fc2,  wT_fc2,  4096, 1024);

    ln_kernel<<<M_ROWS, 256, 0, stream>>>(x, ln1_g, ln1_b, lnbuf);
    gemm_f16<3><<<dim3(3072 / 128, M_ROWS / 128), 256, 0, stream>>>(
        lnbuf, wT_attn, b_attn, nullptr, nullptr, qkbuf, vTbuf, 1024, 3072);
    flash_kernel<<<dim3(16, 64), 256, 0, stream>>>(qkbuf, vTbuf, ybuf);
    gemm_f16<1><<<dim3(1024 / 128, M_ROWS / 128), 256, 0, stream>>>(
        ybuf, wT_proj, b_proj, x, out, nullptr, nullptr, 1024, 1024);
    ln_kernel<<<M_ROWS, 256, 0, stream>>>(out, ln2_g, ln2_b, lnbuf);
    gemm_f16<2><<<dim3(4096 / 128, M_ROWS / 128), 256, 0, stream>>>(
        lnbuf, wT_fc, b_fc, nullptr, nullptr, h, nullptr, 1024, 4096);
    gemm_f16<1><<<dim3(1024 / 128, M_ROWS / 128), 256, 0, stream>>>(
        h, wT_fc2, b_fc2, out, out, nullptr, nullptr, 4096, 1024);
}

// Round 10
// 665.337 us; speedup vs baseline: 1.1637x; 1.0194x over previous
//
#include <hip/hip_runtime.h>
#include <math.h>

// Round 10: r5 (576us config) + flash Ps halved to 32x72/wave => LDS 50KB =>
// 3 blocks/CU. Ordering of the split P halves uses ZERO-INSTRUCTION compiler
// fences only (asm ""::: "memory"): same-wave DS ops execute in order at the
// DS unit, so no runtime s_waitcnt is needed (r9's runtime fences cost 118us
// via VGPR blowup + forced drains). r7's failure is attributed to cross-
// back-edge compiler reordering, which these fences prevent.
// GEMMs/LN/wconv byte-identical to r5.
//
// ws: [0,16M) lnbuf | [16,48M) qk | [48,64M) vT | [64,80M) ybuf
//     [80,144M) h | [144,170M) wT

#define M_ROWS 8192
#define T_SEQ 2048
#define N_EMB 1024
#define N_HEADS 16
#define HEAD_D 64

typedef _Float16 f16;
typedef __attribute__((ext_vector_type(8))) _Float16 f16x8;
typedef __attribute__((ext_vector_type(4))) _Float16 f16x4;
typedef __attribute__((ext_vector_type(4))) float f32x4;

// compiler-only reorder fence: no instruction emitted; prevents the compiler
// from moving LDS accesses across it (runtime ordering = in-order DS pipe).
#define CFENCE() asm volatile("" ::: "memory")

__device__ __forceinline__ void async16(void* lds, const void* g) {
    __builtin_amdgcn_global_load_lds(
        (const __attribute__((address_space(1))) unsigned int*)g,
        (__attribute__((address_space(3))) unsigned int*)lds, 16, 0, 0);
}

__device__ __forceinline__ float gelu_tanh(float v) {
    float u = 0.7978845608028654f * (v + 0.044715f * v * v * v);
    float e = __expf(2.0f * u);
    float t = 1.0f - 2.0f / (e + 1.0f);
    return 0.5f * v * (1.0f + t);
}

// ---------------------------------------------------------------- weight convert
__launch_bounds__(256)
__global__ void wconv_kernel(const float* __restrict__ W, f16* __restrict__ WT,
                             int K, int N) {
    __shared__ float t[32][33];
    int tx = threadIdx.x & 31, ty = threadIdx.x >> 5;
    int n0 = blockIdx.x * 32, k0 = blockIdx.y * 32;
    #pragma unroll
    for (int r = 0; r < 4; r++)
        t[ty * 4 + r][tx] = W[(size_t)(k0 + ty * 4 + r) * N + n0 + tx];
    __syncthreads();
    #pragma unroll
    for (int r = 0; r < 4; r++)
        WT[(size_t)(n0 + ty * 4 + r) * K + k0 + tx] = (f16)t[tx][ty * 4 + r];
}

// ---------------------------------------------------------------- LayerNorm -> f16
__launch_bounds__(256)
__global__ void ln_kernel(const float* __restrict__ x, const float* __restrict__ g,
                          const float* __restrict__ b, f16* __restrict__ y) {
    int row = blockIdx.x;
    int tid = threadIdx.x;
    const float* xr = x + (size_t)row * N_EMB;
    float4 v = *(const float4*)(xr + tid * 4);
    float s  = v.x + v.y + v.z + v.w;
    float sq = v.x * v.x + v.y * v.y + v.z * v.z + v.w * v.w;
    #pragma unroll
    for (int off = 32; off > 0; off >>= 1) {
        s  += __shfl_down(s, off);
        sq += __shfl_down(sq, off);
    }
    __shared__ float ws_[4], wq_[4];
    __shared__ float mean_s, rstd_s;
    int lane = tid & 63, wid = tid >> 6;
    if (lane == 0) { ws_[wid] = s; wq_[wid] = sq; }
    __syncthreads();
    if (tid == 0) {
        float st = ws_[0] + ws_[1] + ws_[2] + ws_[3];
        float qt = wq_[0] + wq_[1] + wq_[2] + wq_[3];
        float mu = st * (1.0f / N_EMB);
        float var = qt * (1.0f / N_EMB) - mu * mu;
        mean_s = mu;
        rstd_s = rsqrtf(var + 1e-5f);
    }
    __syncthreads();
    float mu = mean_s, r = rstd_s;
    float4 gv = *(const float4*)(g + tid * 4);
    float4 bv = *(const float4*)(b + tid * 4);
    f16x4 o;
    o.x = (f16)((v.x - mu) * r * gv.x + bv.x);
    o.y = (f16)((v.y - mu) * r * gv.y + bv.y);
    o.z = (f16)((v.z - mu) * r * gv.z + bv.z);
    o.w = (f16)((v.w - mu) * r * gv.w + bv.w);
    *(f16x4*)(y + (size_t)row * N_EMB + tid * 4) = o;
}

// ---------------------------------------------------------------- GEMM 128x128
// r5 kernel: dbuf LDS, single barrier per k-iter, async prefetch.
// EPI: 0 f32 | 1 f32 + f32 residual | 2 gelu->f16 | 3 qkv split
template <int EPI>
__launch_bounds__(256)
__global__ void gemm_f16(const f16* __restrict__ A, const f16* __restrict__ Bt,
                         const float* __restrict__ bias, const float* __restrict__ res,
                         float* __restrict__ Cf, f16* __restrict__ Ch,
                         f16* __restrict__ vT, int K, int N) {
    __shared__ f16 As[2][128 * 32];
    __shared__ f16 Bs[2][128 * 32];
    int tid = threadIdx.x;
    int lane = tid & 63, wave = tid >> 6;
    int wr = wave >> 1, wc = wave & 1;
    int quad = lane >> 4, l16 = lane & 15;
    int m0 = blockIdx.y * 128, n0 = blockIdx.x * 128;

    int r0 = tid >> 2;
    int s0 = (tid & 3) * 8;
    const f16* paA0 = A  + (size_t)(m0 + r0) * K + s0;
    const f16* paA1 = A  + (size_t)(m0 + r0 + 64) * K + s0;
    const f16* paB0 = Bt + (size_t)(n0 + r0) * K + s0;
    const f16* paB1 = Bt + (size_t)(n0 + r0 + 64) * K + s0;
    char* dA0 = (char*)As + (size_t)tid * 16;
    char* dA1 = (char*)As + (size_t)(256 + tid) * 16;
    char* dB0 = (char*)Bs + (size_t)tid * 16;
    char* dB1 = (char*)Bs + (size_t)(256 + tid) * 16;

    async16(dA0, paA0);
    async16(dA1, paA1);
    async16(dB0, paB0);
    async16(dB1, paB1);

    f32x4 acc[4][4] = {};
    int p = 0;
    for (int k0 = 0; k0 < K; k0 += 32, p ^= 1) {
        __syncthreads();
        if (k0 + 32 < K) {
            int koff = k0 + 32;
            async16(dA0 + (p ^ 1) * 8192, paA0 + koff);
            async16(dA1 + (p ^ 1) * 8192, paA1 + koff);
            async16(dB0 + (p ^ 1) * 8192, paB0 + koff);
            async16(dB1 + (p ^ 1) * 8192, paB1 + koff);
        }
        const f16* as = As[p];
        const f16* bs = Bs[p];
        f16x8 af[4], bf[4];
        #pragma unroll
        for (int i = 0; i < 4; i++)
            af[i] = *(const f16x8*)&as[(wr * 64 + i * 16 + l16) * 32 + quad * 8];
        #pragma unroll
        for (int j = 0; j < 4; j++)
            bf[j] = *(const f16x8*)&bs[(wc * 64 + j * 16 + l16) * 32 + quad * 8];
        #pragma unroll
        for (int i = 0; i < 4; i++)
            #pragma unroll
            for (int j = 0; j < 4; j++)
                acc[i][j] = __builtin_amdgcn_mfma_f32_16x16x32_f16(
                    af[i], bf[j], acc[i][j], 0, 0, 0);
    }

    #pragma unroll
    for (int i = 0; i < 4; i++) {
        int row0 = m0 + wr * 64 + i * 16 + quad * 4;
        #pragma unroll
        for (int j = 0; j < 4; j++) {
            int col = n0 + wc * 64 + j * 16 + l16;
            float bb = bias[col];
            if (EPI == 3) {
                if (n0 < 2048) {
                    #pragma unroll
                    for (int r = 0; r < 4; r++)
                        Ch[(size_t)(row0 + r) * 2048 + col] = (f16)(acc[i][j][r] + bb);
                } else {
                    int hh = (col - 2048) >> 6, dd = col & 63;
                    int bb_ = row0 >> 11, t0 = row0 & 2047;
                    f16x4 pk;
                    pk.x = (f16)(acc[i][j][0] + bb);
                    pk.y = (f16)(acc[i][j][1] + bb);
                    pk.z = (f16)(acc[i][j][2] + bb);
                    pk.w = (f16)(acc[i][j][3] + bb);
                    *(f16x4*)(vT + ((size_t)(bb_ * 16 + hh) * 64 + dd) * 2048 + t0) = pk;
                }
            } else {
                #pragma unroll
                for (int r = 0; r < 4; r++) {
                    size_t idx = (size_t)(row0 + r) * N + col;
                    float v = acc[i][j][r] + bb;
                    if (EPI == 1) v += res[idx];
                    if (EPI == 2) Ch[idx] = (f16)gelu_tanh(v);
                    else          Cf[idx] = v;
                }
            }
        }
    }
}

// ---------------------------------------------------------------- MFMA flash
// r5 structure: 256 thr = 4 waves, 128 q/block, 128-j tiles, K/V staged via
// global_load_lds + 2 barriers/iter. Ps halved to 32x72/wave, halves ordered
// by compiler-only fences (in-order DS pipe handles runtime ordering).
// LDS: 16K Ks + 16K Vs + 18K Ps = 50KB -> 3 blocks/CU.
__launch_bounds__(256)
__global__ void flash_kernel(const f16* __restrict__ qk, const f16* __restrict__ vT,
                             f16* __restrict__ y) {
    __shared__ __align__(16) char smem[51200];
    f16* Ks = (f16*)smem;                      // [128 j][8 g of 8 d], g^=(j&7)
    f16* Vs = (f16*)(smem + 16384);            // [64 d][16 g of 8 j], g^=(d&7)
    int tid = threadIdx.x;
    int lane = tid & 63, w = tid >> 6;
    int quad = lane >> 4, l16 = lane & 15;
    f16* Ps = (f16*)(smem + 32768 + w * 4608); // per-wave [32 q][72], one 64-j half

    int qt = 15 - blockIdx.x;                  // long blocks first
    int bh = blockIdx.y;
    int b = bh >> 4, h = bh & 15;
    int q0 = qt * 128;
    const size_t qkrow = (size_t)b * T_SEQ * 2048;

    // Q B-frags, pre-scaled by 0.125*log2(e) (exp2 softmax)
    const f16 qsc = (f16)0.1803368801f;
    f16x8 qf[2][2];
    #pragma unroll
    for (int qn = 0; qn < 2; qn++) {
        int q = q0 + w * 32 + qn * 16 + l16;
        #pragma unroll
        for (int dblk = 0; dblk < 2; dblk++) {
            f16x8 t = *(const f16x8*)(qk + qkrow + (size_t)q * 2048 +
                                      h * 64 + dblk * 32 + quad * 8);
            #pragma unroll
            for (int e = 0; e < 8; e++) t[e] = t[e] * qsc;
            qf[qn][dblk] = t;
        }
    }

    float m_r[2] = {-INFINITY, -INFINITY};
    float l_r[2] = {0.0f, 0.0f};
    f32x4 Oacc[2][4] = {};

    for (int jt = 0; jt <= qt; jt++) {
        int j0 = jt * 128;
        __syncthreads();   // prev readers of Ks/Vs done
        #pragma unroll
        for (int i = 0; i < 4; i++) {
            int L = i * 256 + tid;
            int j = L >> 3, g1 = L & 7;
            int g = g1 ^ (j & 7);
            async16((char*)Ks + (size_t)L * 16,
                    qk + qkrow + (size_t)(j0 + j) * 2048 + 1024 + h * 64 + g * 8);
        }
        #pragma unroll
        for (int i = 0; i < 4; i++) {
            int L = i * 256 + tid;
            int d = L >> 4, g1 = L & 15;
            int g = (g1 & 8) | ((g1 ^ d) & 7);
            async16((char*)Vs + (size_t)L * 16,
                    vT + ((size_t)bh * 64 + d) * 2048 + j0 + g * 8);
        }
        __syncthreads();   // DMA drained: Ks/Vs ready

        // S^T = K . Q^T
        f32x4 S[8][2];
        #pragma unroll
        for (int jm = 0; jm < 8; jm++) {
            f16x8 kf[2];
            #pragma unroll
            for (int dblk = 0; dblk < 2; dblk++) {
                int j = jm * 16 + l16;
                int g = (dblk * 4 + quad) ^ (j & 7);
                kf[dblk] = *(const f16x8*)(Ks + (size_t)(j * 8 + g) * 8);
            }
            #pragma unroll
            for (int qn = 0; qn < 2; qn++) {
                f32x4 s = {};
                s = __builtin_amdgcn_mfma_f32_16x16x32_f16(kf[0], qf[qn][0], s, 0, 0, 0);
                s = __builtin_amdgcn_mfma_f32_16x16x32_f16(kf[1], qf[qn][1], s, 0, 0, 0);
                S[jm][qn] = s;
            }
        }

        if (jt == qt) {  // diagonal mask: j > q (tile-local)
            #pragma unroll
            for (int jm = 0; jm < 8; jm++)
                #pragma unroll
                for (int qn = 0; qn < 2; qn++)
                    #pragma unroll
                    for (int r = 0; r < 4; r++) {
                        int jl = jm * 16 + quad * 4 + r;
                        int ql = w * 32 + qn * 16 + l16;
                        if (jl > ql) S[jm][qn][r] = -1e30f;
                    }
        }

        // online softmax (exp2 domain)
        float alpha[2];
        #pragma unroll
        for (int qn = 0; qn < 2; qn++) {
            float tmax = -INFINITY;
            #pragma unroll
            for (int jm = 0; jm < 8; jm++)
                #pragma unroll
                for (int r = 0; r < 4; r++)
                    tmax = fmaxf(tmax, S[jm][qn][r]);
            tmax = fmaxf(tmax, __shfl_xor(tmax, 16));
            tmax = fmaxf(tmax, __shfl_xor(tmax, 32));
            float mnew = fmaxf(m_r[qn], tmax);
            alpha[qn] = exp2f(m_r[qn] - mnew);
            m_r[qn] = mnew;
            float rsum = 0.0f;
            #pragma unroll
            for (int jm = 0; jm < 8; jm++)
                #pragma unroll
                for (int r = 0; r < 4; r++) {
                    float pp = exp2f(S[jm][qn][r] - mnew);
                    S[jm][qn][r] = pp;
                    rsum += pp;
                }
            rsum += __shfl_xor(rsum, 16);
            rsum += __shfl_xor(rsum, 32);
            l_r[qn] = l_r[qn] * alpha[qn] + rsum;
        }

        // rescale O by alpha
        float aPV[2][4];
        #pragma unroll
        for (int m = 0; m < 2; m++)
            #pragma unroll
            for (int r = 0; r < 4; r++)
                aPV[m][r] = __shfl(alpha[m], quad * 20 + r);
        #pragma unroll
        for (int m = 0; m < 2; m++)
            #pragma unroll
            for (int n = 0; n < 4; n++)
                #pragma unroll
                for (int r = 0; r < 4; r++)
                    Oacc[m][n][r] *= aPV[m][r];

        // ---- P half 0 (j 0..63): store, then PV kblk 0..1 (in-order DS pipe;
        // CFENCE pins compiler ordering only)
        #pragma unroll
        for (int jm = 0; jm < 4; jm++)
            #pragma unroll
            for (int qn = 0; qn < 2; qn++) {
                f16x4 pk;
                pk.x = (f16)S[jm][qn][0];
                pk.y = (f16)S[jm][qn][1];
                pk.z = (f16)S[jm][qn][2];
                pk.w = (f16)S[jm][qn][3];
                *(f16x4*)(Ps + (size_t)(qn * 16 + l16) * 72 + jm * 16 + quad * 4) = pk;
            }
        CFENCE();
        #pragma unroll
        for (int kblk = 0; kblk < 2; kblk++) {
            f16x8 pf[2];
            #pragma unroll
            for (int m = 0; m < 2; m++)
                pf[m] = *(const f16x8*)(Ps + (size_t)(m * 16 + l16) * 72 +
                                        kblk * 32 + quad * 8);
            f16x8 vf[4];
            #pragma unroll
            for (int n = 0; n < 4; n++) {
                int d = n * 16 + l16;
                int g = kblk * 4 + quad;
                int gs = (g & 8) | ((g ^ d) & 7);
                vf[n] = *(const f16x8*)(Vs + (size_t)(d * 16 + gs) * 8);
            }
            #pragma unroll
            for (int m = 0; m < 2; m++)
                #pragma unroll
                for (int n = 0; n < 4; n++)
                    Oacc[m][n] = __builtin_amdgcn_mfma_f32_16x16x32_f16(
                        pf[m], vf[n], Oacc[m][n], 0, 0, 0);
        }
        CFENCE();

        // ---- P half 1 (j 64..127): overwrite, then PV kblk 2..3
        #pragma unroll
        for (int jm = 4; jm < 8; jm++)
            #pragma unroll
            for (int qn = 0; qn < 2; qn++) {
                f16x4 pk;
                pk.x = (f16)S[jm][qn][0];
                pk.y = (f16)S[jm][qn][1];
                pk.z = (f16)S[jm][qn][2];
                pk.w = (f16)S[jm][qn][3];
                *(f16x4*)(Ps + (size_t)(qn * 16 + l16) * 72 + (jm - 4) * 16 + quad * 4) = pk;
            }
        CFENCE();
        #pragma unroll
        for (int kblk = 2; kblk < 4; kblk++) {
            f16x8 pf[2];
            #pragma unroll
            for (int m = 0; m < 2; m++)
                pf[m] = *(const f16x8*)(Ps + (size_t)(m * 16 + l16) * 72 +
                                        (kblk - 2) * 32 + quad * 8);
            f16x8 vf[4];
            #pragma unroll
            for (int n = 0; n < 4; n++) {
                int d = n * 16 + l16;
                int g = kblk * 4 + quad;
                int gs = (g & 8) | ((g ^ d) & 7);
                vf[n] = *(const f16x8*)(Vs + (size_t)(d * 16 + gs) * 8);
            }
            #pragma unroll
            for (int m = 0; m < 2; m++)
                #pragma unroll
                for (int n = 0; n < 4; n++)
                    Oacc[m][n] = __builtin_amdgcn_mfma_f32_16x16x32_f16(
                        pf[m], vf[n], Oacc[m][n], 0, 0, 0);
        }
        CFENCE();   // P-reads of half1 ordered before next iter's half0 stores
    }

    // epilogue: O / l -> ybuf [B,T,C] f16
    #pragma unroll
    for (int m = 0; m < 2; m++) {
        float lPV[4];
        #pragma unroll
        for (int r = 0; r < 4; r++)
            lPV[r] = 1.0f / __shfl(l_r[m], quad * 20 + r);
        #pragma unroll
        for (int n = 0; n < 4; n++) {
            #pragma unroll
            for (int r = 0; r < 4; r++) {
                int q = q0 + w * 32 + m * 16 + quad * 4 + r;
                y[(size_t)(b * T_SEQ + q) * N_EMB + h * 64 + n * 16 + l16] =
                    (f16)(Oacc[m][n][r] * lPV[r]);
            }
        }
    }
}

// ---------------------------------------------------------------- launch
extern "C" void kernel_launch(void* const* d_in, const int* in_sizes, int n_in,
                              void* d_out, int out_size, void* d_ws, size_t ws_size,
                              hipStream_t stream) {
    const float* x      = (const float*)d_in[0];
    const float* ln1_g  = (const float*)d_in[1];
    const float* ln1_b  = (const float*)d_in[2];
    const float* w_attn = (const float*)d_in[3];
    const float* b_attn = (const float*)d_in[4];
    const float* w_proj = (const float*)d_in[5];
    const float* b_proj = (const float*)d_in[6];
    const float* ln2_g  = (const float*)d_in[7];
    const float* ln2_b  = (const float*)d_in[8];
    const float* w_fc   = (const float*)d_in[9];
    const float* b_fc   = (const float*)d_in[10];
    const float* w_fc2  = (const float*)d_in[11];
    const float* b_fc2  = (const float*)d_in[12];
    float* out = (float*)d_out;

    const size_t MB = 1024 * 1024;
    char* ws = (char*)d_ws;
    f16*   lnbuf = (f16*)ws;                        // 16 MB
    f16*   qkbuf = (f16*)(ws + 16 * MB);            // 32 MB: [M][2048] Q|K
    f16*   vTbuf = (f16*)(ws + 48 * MB);            // 16 MB: [b][h][d][t]
    f16*   ybuf  = (f16*)(ws + 64 * MB);            // 16 MB
    f16*   h     = (f16*)(ws + 80 * MB);            // 64 MB
    f16*   wT    = (f16*)(ws + 144 * MB);           // 26 MB
    f16* wT_attn = wT;
    f16* wT_proj = wT_attn + (size_t)3072 * 1024;
    f16* wT_fc   = wT_proj + (size_t)1024 * 1024;
    f16* wT_fc2  = wT_fc   + (size_t)1024 * 4096;

    wconv_kernel<<<dim3(3072 / 32, 1024 / 32), 256, 0, stream>>>(w_attn, wT_attn, 1024, 3072);
    wconv_kernel<<<dim3(1024 / 32, 1024 / 32), 256, 0, stream>>>(w_proj, wT_proj, 1024, 1024);
    wconv_kernel<<<dim3(4096 / 32, 1024 / 32), 256, 0, stream>>>(w_fc,   wT_fc,   1024, 4096);
    wconv_kernel<<<dim3(1024 / 32, 4096 / 32), 256, 0, stream>>>(w_fc2,  wT_fc2,  4096, 1024);

    ln_kernel<<<M_ROWS, 256, 0, stream>>>(x, ln1_g, ln1_b, lnbuf);
    gemm_f16<3><<<dim3(3072 / 128, M_ROWS / 128), 256, 0, stream>>>(
        lnbuf, wT_attn, b_attn, nullptr, nullptr, qkbuf, vTbuf, 1024, 3072);
    flash_kernel<<<dim3(16, 64), 256, 0, stream>>>(qkbuf, vTbuf, ybuf);
    gemm_f16<1><<<dim3(1024 / 128, M_ROWS / 128), 256, 0, stream>>>(
        ybuf, wT_proj, b_proj, x, out, nullptr, nullptr, 1024, 1024);
    ln_kernel<<<M_ROWS, 256, 0, stream>>>(out, ln2_g, ln2_b, lnbuf);
    gemm_f16<2><<<dim3(4096 / 128, M_ROWS / 128), 256, 0, stream>>>(
        lnbuf, wT_fc, b_fc, nullptr, nullptr, h, nullptr, 1024, 4096);
    gemm_f16<1><<<dim3(1024 / 128, M_ROWS / 128), 256, 0, stream>>>(
        h, wT_fc2, b_fc2, out, out, nullptr, nullptr, 4096, 1024);
}